// Round 3
// baseline (71.447 us; speedup 1.0000x reference)
//
#include <hip/hip_runtime.h>
#include <hip/hip_bf16.h>

typedef __attribute__((ext_vector_type(4))) float f32x4;
typedef __attribute__((ext_vector_type(8))) short bf16x8;
typedef __attribute__((ext_vector_type(4))) short bf16x4;

#define SEQ 2048
#define NB 8
#define NH 4
#define DH 16

// ws layout (bytes)
#define WS_LEN 0                       // 8 * int
#define WS_WP  1024                    // 64*64 bf16 = 8192 B
#define WS_WQ  16384                   // 192*64 bf16 = 24576 B
#define WS_Q   65536                   // NB*NH*SEQ*DH*2 = 2 MiB
#define WS_K   (WS_Q + 2097152)
#define WS_V   (WS_K + 2097152)        // V stored transposed [b][h][dh][s]

#define MFMA16x16x32 __builtin_amdgcn_mfma_f32_16x16x32_bf16

__device__ __forceinline__ short f2bf(float f){
  __hip_bfloat16 h = __float2bfloat16(f);
  return __builtin_bit_cast(short, h);
}

__device__ __forceinline__ bf16x8 pack8(f32x4 a, f32x4 b){
  bf16x8 r;
  r[0]=f2bf(a[0]); r[1]=f2bf(a[1]); r[2]=f2bf(a[2]); r[3]=f2bf(a[3]);
  r[4]=f2bf(b[0]); r[5]=f2bf(b[1]); r[6]=f2bf(b[2]); r[7]=f2bf(b[3]);
  return r;
}

// ---------------------------------------------------------------------------
// prep: blocks 0..7 compute lens[b] from the mask's last query row;
//       block 8 converts W_proj and W_qkv to bf16.
// Mask dtype detected at runtime: u8 / i32 / f32 (byte 2048 + element-0 bits).
// ---------------------------------------------------------------------------
__global__ void prep_kernel(const unsigned char* __restrict__ mask,
                            const float* __restrict__ wproj,
                            const float* __restrict__ wqkv,
                            unsigned char* __restrict__ ws){
  const int tid = threadIdx.x;
  const int bx = blockIdx.x;
  if (bx == 8){
    short* wp = (short*)(ws + WS_WP);
    for (int i = tid; i < 64*64; i += 256) wp[i] = f2bf(wproj[i]);
    short* wq = (short*)(ws + WS_WQ);
    for (int i = tid; i < 192*64; i += 256) wq[i] = f2bf(wqkv[i]);
    return;
  }
  const unsigned w0 = *(const unsigned*)mask;
  // u8 layout: element [0,0,1,0] (byte 2048) is True. i32/f32: that byte is 0.
  const int mode = (mask[2048] != 0) ? 0 : ((w0 == 1u) ? 1 : ((w0 == 0x3f800000u) ? 2 : 0));
  __shared__ int cnt;
  if (tid == 0) cnt = 0;
  __syncthreads();
  const long long rowbase = (long long)bx * SEQ * SEQ + (long long)(SEQ-1) * SEQ;
  int c = 0;
  for (int k = tid; k < SEQ; k += 256){
    const long long e = rowbase + k;
    int nz;
    if (mode == 0)      nz = mask[e] != 0;
    else if (mode == 1) nz = ((const int*)mask)[e] != 0;
    else                nz = ((const float*)mask)[e] != 0.0f;
    c += nz;
  }
  atomicAdd(&cnt, c);
  __syncthreads();
  if (tid == 0) ((int*)ws)[bx] = cnt;
}

// ---------------------------------------------------------------------------
// QKV projection: 256 blocks x 256 thr; wave handles 16 tokens x 192 outputs
// via 16x16x32 MFMA (K=64 -> 2 windows). Weights pre-converted to bf16 by
// prep (no per-wave repack). Writes bf16:
//   Q [b][h][s][16]  (pre-scaled by 0.25*log2(e) so attention uses exp2 directly)
//   K [b][h][s][16]
//   V [b][h][16][s]  (transposed for contiguous PV B-fragments)
// ---------------------------------------------------------------------------
__global__ __launch_bounds__(256) void qkv_kernel(const float* __restrict__ x,
                                                  unsigned char* __restrict__ ws){
  const int tid  = threadIdx.x;
  const int lane = tid & 63;
  const int wv   = tid >> 6;
  const int c    = lane & 15;
  const int g    = lane >> 4;
  const int T0   = blockIdx.x * 64 + wv * 16;
  const f32x4 z = {0.f, 0.f, 0.f, 0.f};

  bf16x8 aw[2];
  {
    const float* xr = x + (long long)(T0 + c) * 64 + g * 8;
    #pragma unroll
    for (int w = 0; w < 2; ++w){
      f32x4 lo = *(const f32x4*)(xr + w*32);
      f32x4 hi = *(const f32x4*)(xr + w*32 + 4);
      aw[w] = pack8(lo, hi);
    }
  }

  const int tokbase = T0 + g*4;
  const int b = tokbase >> 11;
  const int sbase = tokbase & (SEQ-1);
  const short* Wq = (const short*)(ws + WS_WQ);
  short* Qd = (short*)(ws + WS_Q);
  short* Kd = (short*)(ws + WS_K);
  short* Vd = (short*)(ws + WS_V);

  #pragma unroll
  for (int ot = 0; ot < 12; ++ot){
    const short* wr = Wq + (ot*16 + c) * 64 + g * 8;
    bf16x8 b0 = *(const bf16x8*)(wr);
    bf16x8 b1 = *(const bf16x8*)(wr + 32);
    f32x4 acc = z;
    acc = MFMA16x16x32(aw[0], b0, acc, 0, 0, 0);
    acc = MFMA16x16x32(aw[1], b1, acc, 0, 0, 0);
    // D: row (token) = g*4+r, col (o) = ot*16 + c
    if (ot < 4){
      short* dst = Qd + ((long long)(b*NH + ot) * SEQ) * DH + c;
      #pragma unroll
      for (int r = 0; r < 4; ++r)
        dst[(long long)(sbase + r) * DH] = f2bf(acc[r] * (0.25f * 1.44269504f));
    } else if (ot < 8){
      short* dst = Kd + ((long long)(b*NH + (ot-4)) * SEQ) * DH + c;
      #pragma unroll
      for (int r = 0; r < 4; ++r)
        dst[(long long)(sbase + r) * DH] = f2bf(acc[r]);
    } else {
      bf16x4 pk;
      #pragma unroll
      for (int r = 0; r < 4; ++r) pk[r] = f2bf(acc[r]);
      *(bf16x4*)(Vd + ((long long)(b*NH + (ot-8)) * DH + c) * SEQ + sbase) = pk;
    }
  }
}

// ---------------------------------------------------------------------------
// Fused flash attention + output projection.
// grid (64, 8): one 32-row q-tile per block, t = 63-blockIdx.x so the
// heaviest blocks launch first (greedy backfill balances the causal +
// ragged-length skew). 4 waves = 4 heads; ~20KB LDS, so 2+ blocks/CU are
// co-resident -> 2+ waves/SIMD latency hiding.
// Swapped QK^T: S^T = mfma(K_frag, Q^T_frag) (Dh=16 zero-padded to K=32).
// No running max: p = exp2(score) directly (scores pre-scaled to log2 domain;
// max possible |score| ~ tens, far from overflow); normalize once at the end.
// P goes through wave-private XOR-swizzled LDS -> ds_read_b128 A-frags for PV.
// ---------------------------------------------------------------------------
__global__ __launch_bounds__(256) void attn_kernel(const unsigned char* __restrict__ ws,
                                                   const float* __restrict__ bproj,
                                                   float* __restrict__ out){
  const int tid  = threadIdx.x;
  const int lane = tid & 63;
  const int h    = tid >> 6;
  const int c    = lane & 15;
  const int g    = lane >> 4;
  const int t    = 63 - blockIdx.x;   // heavy tiles first
  const int b    = blockIdx.y;
  const int len  = ((const int*)ws)[b];
  const long long bh = (long long)(b*NH + h);
  const short* Q  = (const short*)(ws + WS_Q) + bh * SEQ * DH;
  const short* K  = (const short*)(ws + WS_K) + bh * SEQ * DH;
  const short* Vt = (const short*)(ws + WS_V) + bh * DH * SEQ;
  const short* Wp = (const short*)(ws + WS_WP);

  __shared__ __align__(16) unsigned char smem[4*4096 + 4096];
  const unsigned pbase = h * 4096;
  const unsigned CTXB  = 16384;
  const f32x4 z  = {0.f,0.f,0.f,0.f};
  const bf16x8 zs = {0,0,0,0,0,0,0,0};

  const int q0 = t * 32;

  bf16x8 qf[2];
  #pragma unroll
  for (int qb = 0; qb < 2; ++qb)
    qf[qb] = (g < 2) ? *(const bf16x8*)(Q + (q0 + qb*16 + c)*DH + g*8) : zs;

  f32x4 acc[2] = {z, z};
  f32x4 lsv[2] = {z, z};
  const int kcount = min(q0 + 32, len);     // keys needed by rows q0..q0+31
  const int nkt  = (kcount + 63) >> 6;
  const int icnt = min(q0 >> 6, len >> 6);  // tiles needing no masking

  for (int kt = 0; kt < nkt; ++kt){
    const int k0 = kt * 64;
    bf16x8 ka[4];
    #pragma unroll
    for (int kj = 0; kj < 4; ++kj)
      ka[kj] = (g < 2) ? *(const bf16x8*)(K + (k0 + kj*16 + c)*DH + g*8) : zs;

    // S^T[key][q]: row = kj*16 + g*4 + reg, col = qb*16 + c
    f32x4 st[2][4];
    #pragma unroll
    for (int qb = 0; qb < 2; ++qb)
      #pragma unroll
      for (int kj = 0; kj < 4; ++kj)
        st[qb][kj] = MFMA16x16x32(ka[kj], qf[qb], z, 0, 0, 0);

    if (kt < icnt){
      #pragma unroll
      for (int qb = 0; qb < 2; ++qb){
        const unsigned rb = pbase + (qb*16 + c)*128;
        const unsigned sw = (unsigned)(c & 7) << 4;
        #pragma unroll
        for (int kj = 0; kj < 4; ++kj){
          f32x4 pv;
          bf16x4 pk;
          #pragma unroll
          for (int r = 0; r < 4; ++r){ pv[r] = exp2f(st[qb][kj][r]); pk[r] = f2bf(pv[r]); }
          lsv[qb] += pv;
          *(bf16x4*)&smem[rb + ((unsigned)(kj*32 + g*8) ^ sw)] = pk;
        }
      }
    } else {
      #pragma unroll
      for (int qb = 0; qb < 2; ++qb){
        const int q = q0 + qb*16 + c;
        const unsigned rb = pbase + (qb*16 + c)*128;
        const unsigned sw = (unsigned)(c & 7) << 4;
        #pragma unroll
        for (int kj = 0; kj < 4; ++kj){
          f32x4 pv;
          bf16x4 pk;
          #pragma unroll
          for (int r = 0; r < 4; ++r){
            const int k = k0 + kj*16 + g*4 + r;
            const float e = exp2f(st[qb][kj][r]);
            pv[r] = (k <= q && k < len) ? e : 0.f;
            pk[r] = f2bf(pv[r]);
          }
          lsv[qb] += pv;
          *(bf16x4*)&smem[rb + ((unsigned)(kj*32 + g*8) ^ sw)] = pk;
        }
      }
    }

    // PV: ctx[q][dh] += P[q][k] * V[k][dh]
    bf16x8 vb[2];
    #pragma unroll
    for (int w = 0; w < 2; ++w)
      vb[w] = *(const bf16x8*)(Vt + c*SEQ + k0 + w*32 + g*8);
    #pragma unroll
    for (int qb = 0; qb < 2; ++qb){
      const unsigned rb = pbase + (qb*16 + c)*128;
      const unsigned sw = (unsigned)(c & 7) << 4;
      #pragma unroll
      for (int w = 0; w < 2; ++w){
        bf16x8 pa = *(const bf16x8*)&smem[rb + ((unsigned)(w*64 + g*16) ^ sw)];
        acc[qb] = MFMA16x16x32(pa, vb[w], acc[qb], 0, 0, 0);
      }
    }
  }

  // softmax denominator: horizontal sum + lanes {l, l^16, l^32, l^48}
  float ls[2];
  #pragma unroll
  for (int qb = 0; qb < 2; ++qb){
    ls[qb] = lsv[qb][0] + lsv[qb][1] + lsv[qb][2] + lsv[qb][3];
    ls[qb] += __shfl_xor(ls[qb], 16);
    ls[qb] += __shfl_xor(ls[qb], 32);
  }
  // normalize + write ctx (bf16) to swizzled LDS [q][d]
  #pragma unroll
  for (int qb = 0; qb < 2; ++qb){
    #pragma unroll
    for (int r = 0; r < 4; ++r){
      const float rs = __shfl(ls[qb], g*4 + r);
      const int qw2 = qb*16 + g*4 + r;
      const float cv = acc[qb][r] / rs;
      *(short*)&smem[CTXB + qw2*128 +
          (((unsigned)((h*16 + c)*2)) ^ ((unsigned)(qw2 & 7) << 4))] = f2bf(cv);
    }
  }
  __syncthreads();

  // out = ctx @ W_proj^T + b ; wave handles o-block h*16..h*16+15
  bf16x8 wpf[2];
  #pragma unroll
  for (int w = 0; w < 2; ++w)
    wpf[w] = *(const bf16x8*)(Wp + (h*16 + c)*64 + w*32 + g*8);
  const float bias = bproj[h*16 + c];
  #pragma unroll
  for (int qb = 0; qb < 2; ++qb){
    f32x4 oa = z;
    const unsigned rb = CTXB + (qb*16 + c)*128;
    const unsigned sw = (unsigned)(c & 7) << 4;
    #pragma unroll
    for (int w = 0; w < 2; ++w){
      bf16x8 pa = *(const bf16x8*)&smem[rb + ((unsigned)(w*64 + g*16) ^ sw)];
      oa = MFMA16x16x32(pa, wpf[w], oa, 0, 0, 0);
    }
    #pragma unroll
    for (int r = 0; r < 4; ++r)
      out[((long long)b * SEQ + q0 + qb*16 + g*4 + r) * 64 + h*16 + c] = oa[r] + bias;
  }
}

extern "C" void kernel_launch(void* const* d_in, const int* in_sizes, int n_in,
                              void* d_out, int out_size, void* d_ws, size_t ws_size,
                              hipStream_t stream) {
  const float* x     = (const float*)d_in[0];
  const unsigned char* mask = (const unsigned char*)d_in[1];
  const float* wqkv  = (const float*)d_in[2];
  const float* wproj = (const float*)d_in[3];
  const float* bproj = (const float*)d_in[4];
  float* out = (float*)d_out;
  unsigned char* ws = (unsigned char*)d_ws;

  prep_kernel<<<9, 256, 0, stream>>>(mask, wproj, wqkv, ws);
  qkv_kernel<<<256, 256, 0, stream>>>(x, ws);
  attn_kernel<<<dim3(64, 8), 256, 0, stream>>>(ws, bproj, out);
}

// Round 4
// 50.079 us; speedup vs baseline: 1.4267x; 1.4267x over previous
//
#include <hip/hip_runtime.h>
#include <hip/hip_bf16.h>

typedef __attribute__((ext_vector_type(4))) float f32x4;
typedef __attribute__((ext_vector_type(8))) short bf16x8;
typedef __attribute__((ext_vector_type(4))) short bf16x4;

#define SEQ 2048
#define NH 4
#define DH 16

// ws layout (bytes)
#define WS_LEN 0                       // 8 * int
#define WS_WP  1024                    // 64*64 bf16
#define WS_Q   65536                   // NB*NH*SEQ*DH*2 = 2 MiB
#define WS_K   (WS_Q + 2097152)
#define WS_V   (WS_K + 2097152)        // V transposed [b][h][dh][s]

#define MFMA16x16x32 __builtin_amdgcn_mfma_f32_16x16x32_bf16

__device__ __forceinline__ short f2bf(float f){
  __hip_bfloat16 h = __float2bfloat16(f);
  return __builtin_bit_cast(short, h);
}

__device__ __forceinline__ bf16x8 pack8(f32x4 a, f32x4 b){
  bf16x8 r;
  r[0]=f2bf(a[0]); r[1]=f2bf(a[1]); r[2]=f2bf(a[2]); r[3]=f2bf(a[3]);
  r[4]=f2bf(b[0]); r[5]=f2bf(b[1]); r[6]=f2bf(b[2]); r[7]=f2bf(b[3]);
  return r;
}

// ---------------------------------------------------------------------------
// qkv + prep fused. grid (257, 2) x 256 thr.
//   blocks (x<256, y): QKV projection for tokens x*64.., outputs ot=y*6..y*6+5
//   block (256, 0): lens[b] from mask's last query row (dtype auto-detected)
//   block (256, 1): W_proj -> bf16
// Writes bf16: Q [b][h][s][16] (pre-scaled by 0.25*log2e), K [b][h][s][16],
//              V [b][h][16][s] (transposed).
// ---------------------------------------------------------------------------
__global__ __launch_bounds__(256) void qkv_prep_kernel(const float* __restrict__ x,
                                                       const unsigned char* __restrict__ mask,
                                                       const float* __restrict__ wqkv,
                                                       const float* __restrict__ wproj,
                                                       unsigned char* __restrict__ ws){
  const int tid = threadIdx.x;
  if (blockIdx.x == 256){
    if (blockIdx.y == 1){
      short* wp = (short*)(ws + WS_WP);
      for (int i = tid; i < 64*64; i += 256) wp[i] = f2bf(wproj[i]);
      return;
    }
    // lens: mask dtype u8 / i32 / f32 via byte 2048 + element-0 bit pattern
    const unsigned w0 = *(const unsigned*)mask;
    const int mode = (mask[2048] != 0) ? 0 : ((w0 == 1u) ? 1 : ((w0 == 0x3f800000u) ? 2 : 0));
    __shared__ int cnts[8];
    if (tid < 8) cnts[tid] = 0;
    __syncthreads();
    const int b = tid >> 5, j = tid & 31;
    const long long rowbase = (long long)b * SEQ * SEQ + (long long)(SEQ-1) * SEQ;
    int c = 0;
    if (mode == 0){
      const unsigned* mw = (const unsigned*)(mask + rowbase);
      for (int k = j; k < SEQ/4; k += 32){
        unsigned v = mw[k];
        c += (v & 0xffu ? 1:0) + (v & 0xff00u ? 1:0) + (v & 0xff0000u ? 1:0) + (v & 0xff000000u ? 1:0);
      }
    } else if (mode == 1){
      for (int k = j; k < SEQ; k += 32) c += ((const int*)mask)[rowbase + k] != 0;
    } else {
      for (int k = j; k < SEQ; k += 32) c += ((const float*)mask)[rowbase + k] != 0.0f;
    }
    atomicAdd(&cnts[b], c);
    __syncthreads();
    if (tid < 8) ((int*)ws)[tid] = cnts[tid];
    return;
  }

  const int lane = tid & 63;
  const int wv   = tid >> 6;
  const int c    = lane & 15;
  const int g    = lane >> 4;
  const int T0   = blockIdx.x * 64 + wv * 16;
  const f32x4 z = {0.f, 0.f, 0.f, 0.f};

  bf16x8 aw[2];
  {
    const float* xr = x + (long long)(T0 + c) * 64 + g * 8;
    #pragma unroll
    for (int w = 0; w < 2; ++w){
      f32x4 lo = *(const f32x4*)(xr + w*32);
      f32x4 hi = *(const f32x4*)(xr + w*32 + 4);
      aw[w] = pack8(lo, hi);
    }
  }

  const int tokbase = T0 + g*4;
  const int b = tokbase >> 11;
  const int sbase = tokbase & (SEQ-1);
  short* Qd = (short*)(ws + WS_Q);
  short* Kd = (short*)(ws + WS_K);
  short* Vd = (short*)(ws + WS_V);

  #pragma unroll
  for (int oi = 0; oi < 6; ++oi){
    const int ot = blockIdx.y * 6 + oi;
    const float* wr = wqkv + (ot*16 + c) * 64 + g * 8;
    bf16x8 b0 = pack8(*(const f32x4*)(wr),      *(const f32x4*)(wr + 4));
    bf16x8 b1 = pack8(*(const f32x4*)(wr + 32), *(const f32x4*)(wr + 36));
    f32x4 acc = z;
    acc = MFMA16x16x32(aw[0], b0, acc, 0, 0, 0);
    acc = MFMA16x16x32(aw[1], b1, acc, 0, 0, 0);
    // D: row (token) = g*4+r, col (o) = ot*16 + c
    if (ot < 4){
      short* dst = Qd + ((long long)(b*NH + ot) * SEQ) * DH + c;
      #pragma unroll
      for (int r = 0; r < 4; ++r)
        dst[(long long)(sbase + r) * DH] = f2bf(acc[r] * (0.25f * 1.44269504f));
    } else if (ot < 8){
      short* dst = Kd + ((long long)(b*NH + (ot-4)) * SEQ) * DH + c;
      #pragma unroll
      for (int r = 0; r < 4; ++r)
        dst[(long long)(sbase + r) * DH] = f2bf(acc[r]);
    } else {
      bf16x4 pk;
      #pragma unroll
      for (int r = 0; r < 4; ++r) pk[r] = f2bf(acc[r]);
      *(bf16x4*)(Vd + ((long long)(b*NH + (ot-8)) * DH + c) * SEQ + sbase) = pk;
    }
  }
}

// ---------------------------------------------------------------------------
// Fused flash attention + output projection, key-split across wave pairs.
// grid 512 x 512 thr. Block L: b = L&7, u = L>>3, t = u<32 ? 2u : 63-2(u-32)
// so blocks L and L+256 (which land on the same CU under round-robin
// dispatch) have complementary work (2u+1)+(64-2u)=65 key-tiles.
// 8 waves = 4 heads x 2 key-halves; halves combined via LDS f32 reduction
// (valid: no-max softmax -> partial ctx/denominator are additive).
// Swapped QK^T (Dh=16 zero-padded to K=32); P via wave-private XOR-swizzled
// LDS -> ds_read_b128 A-frags for PV; epilogue = 64x64 proj via MFMA.
// ---------------------------------------------------------------------------
__global__ __launch_bounds__(512, 4) void attn_kernel(const unsigned char* __restrict__ ws,
                                                      const float* __restrict__ bproj,
                                                      float* __restrict__ out){
  const int tid  = threadIdx.x;
  const int lane = tid & 63;
  const int wv   = tid >> 6;     // 0..7
  const int h    = wv & 3;
  const int half = wv >> 2;
  const int c    = lane & 15;
  const int g    = lane >> 4;
  const int L    = blockIdx.x;
  const int b    = L & 7;
  const int u    = L >> 3;
  const int t    = (u < 32) ? (2*u) : (63 - 2*(u - 32));
  const int q0   = t * 32;
  const int len  = ((const int*)ws)[b];
  const long long bh = (long long)(b*NH + h);
  const short* Q  = (const short*)(ws + WS_Q) + bh * SEQ * DH;
  const short* K  = (const short*)(ws + WS_K) + bh * SEQ * DH;
  const short* Vt = (const short*)(ws + WS_V) + bh * DH * SEQ;
  const short* Wp = (const short*)(ws + WS_WP);

  // LDS: [0,32768) 8 wave-private P tiles (32q x 64k bf16, swizzled)
  //      [32768, 41472) CMB f32 [4h][32q][17] (stride-17: conflict-free)
  //      [41472, 41984) LSB f32 [4h][32q]
  //      [41984, 46080) CTXB bf16 [32q][64d] swizzled
  __shared__ __align__(16) unsigned char smem[46080];
  float* CMB = (float*)(smem + 32768);
  float* LSB = (float*)(smem + 41472);
  const unsigned pb   = (unsigned)wv * 4096;
  const unsigned CTXB = 41984;
  const f32x4 z  = {0.f,0.f,0.f,0.f};
  const bf16x8 zs = {0,0,0,0,0,0,0,0};

  bf16x8 qf[2];
  #pragma unroll
  for (int qb = 0; qb < 2; ++qb)
    qf[qb] = (g < 2) ? *(const bf16x8*)(Q + (q0 + qb*16 + c)*DH + g*8) : zs;

  f32x4 acc[2] = {z, z};
  f32x4 lsv[2] = {z, z};
  const int kcount = min(q0 + 32, len);
  const int nkt  = (kcount + 63) >> 6;
  const int icnt = min(q0 >> 6, len >> 6);   // tiles needing no masking
  const int nh0  = nkt >> 1;
  const int kb   = half ? nh0 : 0;
  const int ke   = half ? nkt : nh0;
  const unsigned sw = (unsigned)(c & 7) << 4;

  for (int kt = kb; kt < ke; ++kt){
    const int k0 = kt * 64;
    bf16x8 ka[4];
    #pragma unroll
    for (int kj = 0; kj < 4; ++kj)
      ka[kj] = (g < 2) ? *(const bf16x8*)(K + (k0 + kj*16 + c)*DH + g*8) : zs;
    const bool nomask = kt < icnt;

    #pragma unroll
    for (int qb = 0; qb < 2; ++qb){
      f32x4 st[4];
      #pragma unroll
      for (int kj = 0; kj < 4; ++kj)
        st[kj] = MFMA16x16x32(ka[kj], qf[qb], z, 0, 0, 0);
      const unsigned rb = pb + (qb*16 + c)*128;
      const int q = q0 + qb*16 + c;
      #pragma unroll
      for (int kj = 0; kj < 4; ++kj){
        f32x4 pv; bf16x4 pk;
        #pragma unroll
        for (int r = 0; r < 4; ++r){
          float e = exp2f(st[kj][r]);
          if (!nomask){
            const int k = k0 + kj*16 + g*4 + r;
            e = (k <= q && k < len) ? e : 0.f;
          }
          pv[r] = e; pk[r] = f2bf(e);
        }
        lsv[qb] += pv;
        *(bf16x4*)&smem[rb + ((unsigned)(kj*32 + g*8) ^ sw)] = pk;
      }
    }

    bf16x8 vb[2];
    #pragma unroll
    for (int w = 0; w < 2; ++w)
      vb[w] = *(const bf16x8*)(Vt + c*SEQ + k0 + w*32 + g*8);
    #pragma unroll
    for (int qb = 0; qb < 2; ++qb){
      const unsigned rb = pb + (qb*16 + c)*128;
      #pragma unroll
      for (int w = 0; w < 2; ++w){
        bf16x8 pa = *(const bf16x8*)&smem[rb + ((unsigned)(w*64 + g*16) ^ sw)];
        acc[qb] = MFMA16x16x32(pa, vb[w], acc[qb], 0, 0, 0);
      }
    }
  }

  // partial row-sums: lanes {l, l^16, l^32, l^48} cover this half's keys
  float ls[2];
  #pragma unroll
  for (int qb = 0; qb < 2; ++qb){
    ls[qb] = lsv[qb][0] + lsv[qb][1] + lsv[qb][2] + lsv[qb][3];
    ls[qb] += __shfl_xor(ls[qb], 16);
    ls[qb] += __shfl_xor(ls[qb], 32);
  }

  if (half == 0){
    #pragma unroll
    for (int qb = 0; qb < 2; ++qb){
      #pragma unroll
      for (int r = 0; r < 4; ++r)
        CMB[(h*32 + qb*16 + g*4 + r)*17 + c] = acc[qb][r];
      if (g == 0) LSB[h*32 + qb*16 + c] = ls[qb];
    }
  }
  __syncthreads();
  if (half == 1){
    #pragma unroll
    for (int qb = 0; qb < 2; ++qb){
      #pragma unroll
      for (int r = 0; r < 4; ++r){
        const int q = qb*16 + g*4 + r;
        const float tot = acc[qb][r] + CMB[(h*32 + q)*17 + c];
        const float lsT = LSB[h*32 + q] + __shfl(ls[qb], g*4 + r);
        const float cv  = tot / lsT;
        *(short*)&smem[CTXB + q*128 +
            (((unsigned)((h*16 + c)*2)) ^ ((unsigned)(q & 7) << 4))] = f2bf(cv);
      }
    }
  }
  __syncthreads();

  // out = ctx @ W_proj^T + bias; wave (h,half): o-cols h*16.., q-rows half*16..
  bf16x8 wpf[2];
  #pragma unroll
  for (int w = 0; w < 2; ++w)
    wpf[w] = *(const bf16x8*)(Wp + (h*16 + c)*64 + w*32 + g*8);
  const float bias = bproj[h*16 + c];
  f32x4 oa = z;
  const unsigned rb = CTXB + (half*16 + c)*128;
  #pragma unroll
  for (int w = 0; w < 2; ++w){
    bf16x8 pa = *(const bf16x8*)&smem[rb + ((unsigned)(w*64 + g*16) ^ sw)];
    oa = MFMA16x16x32(pa, wpf[w], oa, 0, 0, 0);
  }
  #pragma unroll
  for (int r = 0; r < 4; ++r)
    out[((long long)b * SEQ + q0 + half*16 + g*4 + r) * 64 + h*16 + c] = oa[r] + bias;
}

extern "C" void kernel_launch(void* const* d_in, const int* in_sizes, int n_in,
                              void* d_out, int out_size, void* d_ws, size_t ws_size,
                              hipStream_t stream) {
  const float* x     = (const float*)d_in[0];
  const unsigned char* mask = (const unsigned char*)d_in[1];
  const float* wqkv  = (const float*)d_in[2];
  const float* wproj = (const float*)d_in[3];
  const float* bproj = (const float*)d_in[4];
  float* out = (float*)d_out;
  unsigned char* ws = (unsigned char*)d_ws;

  qkv_prep_kernel<<<dim3(257, 2), 256, 0, stream>>>(x, mask, wqkv, wproj, ws);
  attn_kernel<<<512, 512, 0, stream>>>(ws, bproj, out);
}